// Round 14
// baseline (298.904 us; speedup 1.0000x reference)
//
#include <hip/hip_runtime.h>

#define F 64
#define H 64
#define NT 256
#define TILE_ROWS 128     // 4 waves x 32 wave-private rows
#define ITERS 8
#define ROWS_PER_BLOCK (TILE_ROWS * ITERS)   // 1024
#define WPAD 72           // LDS row stride in bf16 elems (144 B)

typedef __bf16 bf16;
typedef __attribute__((ext_vector_type(8))) __bf16 bf16x8;
typedef __attribute__((ext_vector_type(4))) __bf16 bf16x4;
typedef __attribute__((ext_vector_type(4))) float f32x4;

__device__ __forceinline__ float celu1(float v) {
    // CELU(alpha=1): x>0 ? x : exp(x)-1
    float e = __expf(v) - 1.0f;
    return v > 0.0f ? v : e;
}

// Single kernel, (NT,3) -- the 128-reg cap (min-waves=4) spilled in all four attempts
// (R4/R5/R9/R13; signature: reported VGPR==64 + FETCH_SIZE>300MB scratch traffic).
// Block = one feature f x 1024 rows; 4 waves x 32 rows; ZERO per-tile LDS data traffic:
//  - layer-in is rank-1 -> per-lane scalar FMA directly into hidden-0's B-fragments.
//  - hidden-0 -> hidden-1 hand-off uses MFMA k-permutation invariance: with k-order
//    k' = 16*(j>>1) + 4q + 2kk + (j&1) for hidden-1 (weights stored permuted in LDS at
//    staging), hidden-0's D fragment IS hidden-1's B fragment (register repack only).
//    Each of the two k-slices sums a disjoint 32-set of k -> exact same dot product.
//  - hidden-1 output dotted with w_out in registers (w_out indexed by out=16m+4q+rr,
//    matching D layout), quad shfl-reduce, store.
// LDS = weights (wlds[0] natural, wlds[1] permuted) + hidden biases = ~19 KB; one barrier.
__global__ __launch_bounds__(NT, 3) void mlp64(
    const float* __restrict__ x,      // [B,F]
    const float* __restrict__ w_in,
    const float* __restrict__ b_in,
    const float* __restrict__ w_hid,
    const float* __restrict__ b_hid,
    const float* __restrict__ w_out,
    const float* __restrict__ b_out,
    float* __restrict__ out,          // [B,F]
    int Btot)
{
    const int f    = blockIdx.x & (F - 1);
    const int blk  = blockIdx.x >> 6;
    const int row0 = blk * ROWS_PER_BLOCK;
    const int t    = threadIdx.x;
    const int lane = t & 63;
    const int l15  = lane & 15;
    const int q    = lane >> 4;
    const int wrow = (t >> 6) * 32;   // wave-private 32-row slice

    __shared__ __align__(16) bf16 wlds[2][H][WPAD];   // [0]=hidden0 natural, [1]=hidden1 k-permuted
    __shared__ __align__(16) float s_bias[2][H];      // hidden biases

    // ---- stage weights (fp32 -> bf16); wlds[1] gets the k-permuted layout ----
    for (int idx = t; idx < 1024; idx += NT) {
        const int l = idx >> 9, rc = idx & 511, row = rc >> 3, c = rc & 7;
        if (l == 0) {
            const float* p = w_hid + ((size_t)f << 12) + (row << 6) + (c << 3);
            float4 a = *(const float4*)p, b = *(const float4*)(p + 4);
            bf16x8 v;
            v[0] = (bf16)a.x; v[1] = (bf16)a.y; v[2] = (bf16)a.z; v[3] = (bf16)a.w;
            v[4] = (bf16)b.x; v[5] = (bf16)b.y; v[6] = (bf16)b.z; v[7] = (bf16)b.w;
            *(bf16x8*)&wlds[0][row][c * 8] = v;
        } else {
            // c = qq*2 + kk; dst chunk [qq*16 + kk*8 + j] <- W1[row][16*(j>>1) + 4qq + 2kk + (j&1)]
            const int qq = c >> 1, kk = c & 1, base = 4 * qq + 2 * kk;
            const float* p = w_hid + (((size_t)F + f) << 12) + (row << 6) + base;
            bf16x8 v;
            #pragma unroll
            for (int mp = 0; mp < 4; ++mp) {
                float2 pr = *(const float2*)(p + 16 * mp);
                v[2 * mp]     = (bf16)pr.x;
                v[2 * mp + 1] = (bf16)pr.y;
            }
            *(bf16x8*)&wlds[1][row][qq * 16 + kk * 8] = v;
        }
    }
    if (t < H)          s_bias[0][t]     = b_hid[f * H + t];
    else if (t < 2 * H) s_bias[1][t - H] = b_hid[F * H + f * H + (t - H)];
    __syncthreads();

    // ---- per-lane layer-in weights/biases: in-index = 32kk + 8q + j ----
    float w16[16], b16[16];
    {
        const float* wp = w_in + f * H + q * 8;
        const float* bp = b_in + f * H + q * 8;
        #pragma unroll
        for (int kk = 0; kk < 2; ++kk) {
            float4 a = *(const float4*)(wp + kk * 32), b = *(const float4*)(wp + kk * 32 + 4);
            float4 c = *(const float4*)(bp + kk * 32), d = *(const float4*)(bp + kk * 32 + 4);
            w16[kk*8+0]=a.x; w16[kk*8+1]=a.y; w16[kk*8+2]=a.z; w16[kk*8+3]=a.w;
            w16[kk*8+4]=b.x; w16[kk*8+5]=b.y; w16[kk*8+6]=b.z; w16[kk*8+7]=b.w;
            b16[kk*8+0]=c.x; b16[kk*8+1]=c.y; b16[kk*8+2]=c.z; b16[kk*8+3]=c.w;
            b16[kk*8+4]=d.x; b16[kk*8+5]=d.y; b16[kk*8+6]=d.z; b16[kk*8+7]=d.w;
        }
    }

    f32x4 wo4[4];
    #pragma unroll
    for (int m = 0; m < 4; ++m)
        wo4[m] = *(const f32x4*)(w_out + f * H + m * 16 + q * 4);
    const float bo = b_out[f];

    float xc0 = x[(size_t)(row0 + wrow + l15) * F + f];
    float xc1 = x[(size_t)(row0 + wrow + 16 + l15) * F + f];

    #pragma unroll 1
    for (int it = 0; it < ITERS; ++it) {
        const int rbase = row0 + it * TILE_ROWS + wrow;

        float xn0 = 0.0f, xn1 = 0.0f;
        if (it + 1 < ITERS) {
            xn0 = x[(size_t)(rbase + TILE_ROWS + l15) * F + f];
            xn1 = x[(size_t)(rbase + TILE_ROWS + 16 + l15) * F + f];
        }

        // ---- layer in->H: rank-1 -> hidden-0 B-fragments (exact fp32) ----
        bf16x8 Bh[2][2];   // [n][kk]: B[k=32kk+8q+j][batch=n*16+l15]
        #pragma unroll
        for (int n = 0; n < 2; ++n) {
            const float xv = n ? xc1 : xc0;
            #pragma unroll
            for (int kk = 0; kk < 2; ++kk) {
                bf16x8 v;
                #pragma unroll
                for (int j = 0; j < 8; ++j)
                    v[j] = (bf16)celu1(fmaf(xv, w16[kk * 8 + j], b16[kk * 8 + j]));
                Bh[n][kk] = v;
            }
        }

        // ---- hidden layer 0 (natural k-order); keep ALL acc live for the hand-off ----
        f32x4 acc0[4][2];
        #pragma unroll
        for (int m = 0; m < 4; ++m) {
            bf16x8 A0 = *(const bf16x8*)&wlds[0][m * 16 + l15][q * 8];
            bf16x8 A1 = *(const bf16x8*)&wlds[0][m * 16 + l15][32 + q * 8];
            f32x4 c0  = *(const f32x4*)&s_bias[0][m * 16 + q * 4];
            #pragma unroll
            for (int n = 0; n < 2; ++n) {
                f32x4 a = __builtin_amdgcn_mfma_f32_16x16x32_bf16(A0, Bh[n][0], c0, 0, 0, 0);
                acc0[m][n] = __builtin_amdgcn_mfma_f32_16x16x32_bf16(A1, Bh[n][1], a, 0, 0, 0);
            }
        }

        // ---- hand-off: D0 -> hidden-1 B-fragments via k-permutation (register repack) ----
        bf16x8 Bg[2][2];   // [n][kk]: slot j holds celu(acc0[j>>1][n][2kk+(j&1)])
        #pragma unroll
        for (int n = 0; n < 2; ++n)
            #pragma unroll
            for (int kk = 0; kk < 2; ++kk) {
                bf16x8 v;
                #pragma unroll
                for (int j = 0; j < 8; ++j)
                    v[j] = (bf16)celu1(acc0[j >> 1][n][2 * kk + (j & 1)]);
                Bg[n][kk] = v;
            }

        // ---- hidden layer 1 (permuted weights) + output dot in registers ----
        {
            float s0 = 0.0f, s1 = 0.0f;
            #pragma unroll
            for (int m = 0; m < 4; ++m) {
                bf16x8 A0 = *(const bf16x8*)&wlds[1][m * 16 + l15][q * 16];
                bf16x8 A1 = *(const bf16x8*)&wlds[1][m * 16 + l15][q * 16 + 8];
                f32x4 c0  = *(const f32x4*)&s_bias[1][m * 16 + q * 4];
                f32x4 a0 = __builtin_amdgcn_mfma_f32_16x16x32_bf16(A0, Bg[0][0], c0, 0, 0, 0);
                a0       = __builtin_amdgcn_mfma_f32_16x16x32_bf16(A1, Bg[0][1], a0, 0, 0, 0);
                f32x4 a1 = __builtin_amdgcn_mfma_f32_16x16x32_bf16(A0, Bg[1][0], c0, 0, 0, 0);
                a1       = __builtin_amdgcn_mfma_f32_16x16x32_bf16(A1, Bg[1][1], a1, 0, 0, 0);
                #pragma unroll
                for (int rr = 0; rr < 4; ++rr) {
                    s0 = fmaf(celu1(a0[rr]), wo4[m][rr], s0);
                    s1 = fmaf(celu1(a1[rr]), wo4[m][rr], s1);
                }
            }
            s0 += __shfl_xor(s0, 16, 64);
            s0 += __shfl_xor(s0, 32, 64);
            s1 += __shfl_xor(s1, 16, 64);
            s1 += __shfl_xor(s1, 32, 64);
            if (q == 0) {
                out[(size_t)(rbase + l15) * F + f]      = s0 + bo;
                out[(size_t)(rbase + 16 + l15) * F + f] = s1 + bo;
            }
        }

        xc0 = xn0; xc1 = xn1;
    }
}

extern "C" void kernel_launch(void* const* d_in, const int* in_sizes, int n_in,
                              void* d_out, int out_size, void* d_ws, size_t ws_size,
                              hipStream_t stream) {
    const float* x     = (const float*)d_in[0];
    const float* w_in  = (const float*)d_in[1];
    const float* b_in  = (const float*)d_in[2];
    const float* w_hid = (const float*)d_in[3];
    const float* b_hid = (const float*)d_in[4];
    const float* w_out = (const float*)d_in[5];
    const float* b_out = (const float*)d_in[6];
    float* out = (float*)d_out;

    const int Btot = in_sizes[0] / F;                       // 32768
    dim3 grid((unsigned)((Btot / ROWS_PER_BLOCK) * F));     // 2048 blocks
    dim3 block(NT);
    mlp64<<<grid, block, 0, stream>>>(x, w_in, b_in, w_hid, b_hid, w_out, b_out, out, Btot);
}

// Round 15
// 188.600 us; speedup vs baseline: 1.5849x; 1.5849x over previous
//
#include <hip/hip_runtime.h>

#define F 64
#define H 64
#define NT 256
#define TILE_ROWS 128     // 4 waves x 32 wave-private rows
#define ITERS 8
#define ROWS_PER_BLOCK (TILE_ROWS * ITERS)   // 1024
#define WPAD 72           // LDS row stride in bf16 elems (144 B)

typedef __bf16 bf16;
typedef __attribute__((ext_vector_type(8))) __bf16 bf16x8;
typedef __attribute__((ext_vector_type(4))) float f32x4;

__device__ __forceinline__ float celu1(float v) {
    // CELU(alpha=1): x>0 ? x : exp(x)-1
    float e = __expf(v) - 1.0f;
    return v > 0.0f ? v : e;
}

// R14 structure (zero per-tile LDS data traffic) with the spill fixed: the hidden-0
// accumulator is released per-m by fusing the k-permutation repack into the m-loop
// (R14 kept all 32 acc regs live across the hand-off -> ~190 live > the 170 cap ->
// 618MB scratch FETCH).
//  - layer-in (rank-1): per-lane fp32 FMA directly into hidden-0 B-fragments.
//  - hidden-0 -> hidden-1: MFMA k-permutation invariance. k' = 16*(j>>1)+4q+2kk+(j&1);
//    wlds[1] stores W1 with that k-order, so D0 is B1 after a per-m register repack:
//    Bg[n][kk][2m+(0|1)] = celu(acc0[m][n][2kk+(0|1)]). Disjoint k-sets per slice ->
//    exact same dot product (validated R14, absmax 3.9e-3).
//  - hidden-1 + output dot in registers (w_out indexed out=16m+4q+rr = D rows),
//    quad shfl-reduce, store.
// (NT,3): cap 170. min-waves=4 (cap 128) spilled in ALL FOUR attempts (R4/R5/R9/R13)
// -- do not retry. Spill signature: FETCH_SIZE>300MB + WRITE>150MB scratch traffic.
__global__ __launch_bounds__(NT, 3) void mlp64(
    const float* __restrict__ x,      // [B,F]
    const float* __restrict__ w_in,
    const float* __restrict__ b_in,
    const float* __restrict__ w_hid,
    const float* __restrict__ b_hid,
    const float* __restrict__ w_out,
    const float* __restrict__ b_out,
    float* __restrict__ out,          // [B,F]
    int Btot)
{
    const int f    = blockIdx.x & (F - 1);
    const int blk  = blockIdx.x >> 6;
    const int row0 = blk * ROWS_PER_BLOCK;
    const int t    = threadIdx.x;
    const int lane = t & 63;
    const int l15  = lane & 15;
    const int q    = lane >> 4;
    const int wrow = (t >> 6) * 32;   // wave-private 32-row slice

    __shared__ __align__(16) bf16 wlds[2][H][WPAD];   // [0]=hidden0 natural, [1]=hidden1 k-permuted
    __shared__ __align__(16) float s_bias[2][H];      // hidden biases

    // ---- stage weights (fp32 -> bf16); wlds[1] gets the k-permuted layout ----
    for (int idx = t; idx < 1024; idx += NT) {
        const int l = idx >> 9, rc = idx & 511, row = rc >> 3, c = rc & 7;
        if (l == 0) {
            const float* p = w_hid + ((size_t)f << 12) + (row << 6) + (c << 3);
            float4 a = *(const float4*)p, b = *(const float4*)(p + 4);
            bf16x8 v;
            v[0] = (bf16)a.x; v[1] = (bf16)a.y; v[2] = (bf16)a.z; v[3] = (bf16)a.w;
            v[4] = (bf16)b.x; v[5] = (bf16)b.y; v[6] = (bf16)b.z; v[7] = (bf16)b.w;
            *(bf16x8*)&wlds[0][row][c * 8] = v;
        } else {
            // c = qq*2 + kk; dst chunk [qq*16 + kk*8 + j] <- W1[row][16*(j>>1) + 4qq + 2kk + (j&1)]
            const int qq = c >> 1, kk = c & 1, base = 4 * qq + 2 * kk;
            const float* p = w_hid + (((size_t)F + f) << 12) + (row << 6) + base;
            bf16x8 v;
            #pragma unroll
            for (int mp = 0; mp < 4; ++mp) {
                float2 pr = *(const float2*)(p + 16 * mp);
                v[2 * mp]     = (bf16)pr.x;
                v[2 * mp + 1] = (bf16)pr.y;
            }
            *(bf16x8*)&wlds[1][row][qq * 16 + kk * 8] = v;
        }
    }
    if (t < H)          s_bias[0][t]     = b_hid[f * H + t];
    else if (t < 2 * H) s_bias[1][t - H] = b_hid[F * H + f * H + (t - H)];
    __syncthreads();

    // ---- per-lane layer-in weights/biases: in-index = 32kk + 8q + j ----
    float w16[16], b16[16];
    {
        const float* wp = w_in + f * H + q * 8;
        const float* bp = b_in + f * H + q * 8;
        #pragma unroll
        for (int kk = 0; kk < 2; ++kk) {
            float4 a = *(const float4*)(wp + kk * 32), b = *(const float4*)(wp + kk * 32 + 4);
            float4 c = *(const float4*)(bp + kk * 32), d = *(const float4*)(bp + kk * 32 + 4);
            w16[kk*8+0]=a.x; w16[kk*8+1]=a.y; w16[kk*8+2]=a.z; w16[kk*8+3]=a.w;
            w16[kk*8+4]=b.x; w16[kk*8+5]=b.y; w16[kk*8+6]=b.z; w16[kk*8+7]=b.w;
            b16[kk*8+0]=c.x; b16[kk*8+1]=c.y; b16[kk*8+2]=c.z; b16[kk*8+3]=c.w;
            b16[kk*8+4]=d.x; b16[kk*8+5]=d.y; b16[kk*8+6]=d.z; b16[kk*8+7]=d.w;
        }
    }

    f32x4 wo4[4];
    #pragma unroll
    for (int m = 0; m < 4; ++m)
        wo4[m] = *(const f32x4*)(w_out + f * H + m * 16 + q * 4);
    const float bo = b_out[f];

    float xc0 = x[(size_t)(row0 + wrow + l15) * F + f];
    float xc1 = x[(size_t)(row0 + wrow + 16 + l15) * F + f];

    #pragma unroll 1
    for (int it = 0; it < ITERS; ++it) {
        const int rbase = row0 + it * TILE_ROWS + wrow;

        float xn0 = 0.0f, xn1 = 0.0f;
        if (it + 1 < ITERS) {
            xn0 = x[(size_t)(rbase + TILE_ROWS + l15) * F + f];
            xn1 = x[(size_t)(rbase + TILE_ROWS + 16 + l15) * F + f];
        }

        // ---- layer in->H: rank-1 -> hidden-0 B-fragments (exact fp32) ----
        bf16x8 Bh[2][2];   // [n][kk]: B[k=32kk+8q+j][batch=n*16+l15]
        #pragma unroll
        for (int n = 0; n < 2; ++n) {
            const float xv = n ? xc1 : xc0;
            #pragma unroll
            for (int kk = 0; kk < 2; ++kk) {
                bf16x8 v;
                #pragma unroll
                for (int j = 0; j < 8; ++j)
                    v[j] = (bf16)celu1(fmaf(xv, w16[kk * 8 + j], b16[kk * 8 + j]));
                Bh[n][kk] = v;
            }
        }

        // ---- hidden layer 0 fused with the k-permutation repack: acc released per m ----
        bf16x8 Bg[2][2];   // hidden-1 B frags, filled 2 slots per (m,kk)
        #pragma unroll
        for (int m = 0; m < 4; ++m) {
            bf16x8 A0 = *(const bf16x8*)&wlds[0][m * 16 + l15][q * 8];
            bf16x8 A1 = *(const bf16x8*)&wlds[0][m * 16 + l15][32 + q * 8];
            f32x4 c0  = *(const f32x4*)&s_bias[0][m * 16 + q * 4];
            #pragma unroll
            for (int n = 0; n < 2; ++n) {
                f32x4 a = __builtin_amdgcn_mfma_f32_16x16x32_bf16(A0, Bh[n][0], c0, 0, 0, 0);
                a       = __builtin_amdgcn_mfma_f32_16x16x32_bf16(A1, Bh[n][1], a, 0, 0, 0);
                // Bg[n][kk][2m+(j&1)] = celu(a[2kk+(j&1)])
                Bg[n][0][2 * m]     = (bf16)celu1(a[0]);
                Bg[n][0][2 * m + 1] = (bf16)celu1(a[1]);
                Bg[n][1][2 * m]     = (bf16)celu1(a[2]);
                Bg[n][1][2 * m + 1] = (bf16)celu1(a[3]);
            }
        }

        // ---- hidden layer 1 (permuted weights) + output dot in registers ----
        {
            float s0 = 0.0f, s1 = 0.0f;
            #pragma unroll
            for (int m = 0; m < 4; ++m) {
                bf16x8 A0 = *(const bf16x8*)&wlds[1][m * 16 + l15][q * 16];
                bf16x8 A1 = *(const bf16x8*)&wlds[1][m * 16 + l15][q * 16 + 8];
                f32x4 c0  = *(const f32x4*)&s_bias[1][m * 16 + q * 4];
                f32x4 a0 = __builtin_amdgcn_mfma_f32_16x16x32_bf16(A0, Bg[0][0], c0, 0, 0, 0);
                a0       = __builtin_amdgcn_mfma_f32_16x16x32_bf16(A1, Bg[0][1], a0, 0, 0, 0);
                f32x4 a1 = __builtin_amdgcn_mfma_f32_16x16x32_bf16(A0, Bg[1][0], c0, 0, 0, 0);
                a1       = __builtin_amdgcn_mfma_f32_16x16x32_bf16(A1, Bg[1][1], a1, 0, 0, 0);
                #pragma unroll
                for (int rr = 0; rr < 4; ++rr) {
                    s0 = fmaf(celu1(a0[rr]), wo4[m][rr], s0);
                    s1 = fmaf(celu1(a1[rr]), wo4[m][rr], s1);
                }
            }
            s0 += __shfl_xor(s0, 16, 64);
            s0 += __shfl_xor(s0, 32, 64);
            s1 += __shfl_xor(s1, 16, 64);
            s1 += __shfl_xor(s1, 32, 64);
            if (q == 0) {
                out[(size_t)(rbase + l15) * F + f]      = s0 + bo;
                out[(size_t)(rbase + 16 + l15) * F + f] = s1 + bo;
            }
        }

        xc0 = xn0; xc1 = xn1;
    }
}

extern "C" void kernel_launch(void* const* d_in, const int* in_sizes, int n_in,
                              void* d_out, int out_size, void* d_ws, size_t ws_size,
                              hipStream_t stream) {
    const float* x     = (const float*)d_in[0];
    const float* w_in  = (const float*)d_in[1];
    const float* b_in  = (const float*)d_in[2];
    const float* w_hid = (const float*)d_in[3];
    const float* b_hid = (const float*)d_in[4];
    const float* w_out = (const float*)d_in[5];
    const float* b_out = (const float*)d_in[6];
    float* out = (float*)d_out;

    const int Btot = in_sizes[0] / F;                       // 32768
    dim3 grid((unsigned)((Btot / ROWS_PER_BLOCK) * F));     // 2048 blocks
    dim3 block(NT);
    mlp64<<<grid, block, 0, stream>>>(x, w_in, b_in, w_hid, b_hid, w_out, b_out, out, Btot);
}